// Round 1
// baseline (222.785 us; speedup 1.0000x reference)
//
#include <hip/hip_runtime.h>
#include <hip/hip_bf16.h>
#include <stdint.h>

// ---------------- types ----------------
typedef float  f32x16 __attribute__((ext_vector_type(16)));
typedef __bf16 bf16x8 __attribute__((ext_vector_type(8)));

// ---------------- workspace layout (bytes) ----------------
// Qg  bf16 [16][4096][64]  (Q pre-scaled by log2e/8 via Wq)
// Kg  bf16 [16][4096][64]
// Vtg bf16 [16][64][4096]  (V transposed per (b,h))
// attn bf16 [8192][512]
// Wt  bf16 3x[512][64]  (Wq^T,Wk^T,Wv^T)
// Wut bf16 [64][512]
#define WS_QG    0
#define WS_KG    8388608
#define WS_VTG   16777216
#define WS_ATTN  25165824
#define WS_WT    33554432
#define WS_WUT   33751040
// total 33816576 bytes

__device__ __forceinline__ f32x16 zero16(){
  f32x16 z;
  #pragma unroll
  for (int i = 0; i < 16; ++i) z[i] = 0.0f;
  return z;
}

__device__ __forceinline__ uint16_t bf16b(float v){
  return __builtin_bit_cast(uint16_t, __float2bfloat16(v));
}

// pack two floats to packed bf16 (compiler emits cvt+pack; per guide m240 do
// NOT hand-write v_cvt_pk_bf16_f32)
__device__ __forceinline__ uint32_t pk2(float a, float b){
  return (uint32_t)bf16b(a) | ((uint32_t)bf16b(b) << 16);
}

// exchange upper half-lanes of a with lower half-lanes of b:
// after: a = {a.lo, b.lo}, b = {a.hi, b.hi}  (per-lane view across lane^32)
__device__ __forceinline__ void plswap(uint32_t &a, uint32_t &b){
  asm volatile("v_permlane32_swap_b32 %0, %1" : "+v"(a), "+v"(b));
}

// ---------------- kernel 0: weight prep ----------------
__global__ void prep_w(const float* __restrict__ Wq, const float* __restrict__ Wk,
                       const float* __restrict__ Wv, const float* __restrict__ Wu,
                       char* __restrict__ ws){
  int tid = blockIdx.x * 256 + threadIdx.x;   // grid 512*256 = 131072
  if (tid < 3*32768){
    int which = tid >> 15;
    int idx   = tid & 32767;
    int e = idx & 511, k = idx >> 9;
    const float* W = (which == 0) ? Wq : (which == 1 ? Wk : Wv);
    float v = W[k*512 + e];
    if (which == 0) v *= 0.18033688011112042f;   // (1/8) * log2(e) folded into Q
    ((uint16_t*)(ws + WS_WT))[which*32768 + e*64 + k] = bf16b(v);
  } else {
    int idx = tid - 3*32768;
    int c = idx & 63, e = idx >> 6;
    ((uint16_t*)(ws + WS_WUT))[c*512 + e] = bf16b(Wu[e*64 + c]);
  }
}

// ---------------- kernel 1: QKV projection (MFMA) ----------------
// wave task: (row-tile rt of 32, matrix mm in {Q,K,V}, col-block cb of 64)
__global__ __launch_bounds__(256,2) void qkv_proj(const float* __restrict__ x,
                                                  char* __restrict__ ws){
  const int lane = threadIdx.x & 63;
  const int wid  = blockIdx.x*4 + (threadIdx.x >> 6);   // 0..6143
  const int rt   = wid / 24;
  const int rem  = wid % 24;
  const int mm   = rem >> 3, cb = rem & 7;
  const int col  = lane & 31, hi = lane >> 5;

  const uint16_t* Wt = (const uint16_t*)(ws + WS_WT) + mm*32768;

  // A-frags: x rows (fp32 -> bf16).  A: row = lane&31, k = (lane>>5)*8 + i (+16*ks)
  bf16x8 af[4];
  {
    const float* xr = x + (size_t)(rt*32 + col)*64 + hi*8;
    #pragma unroll
    for (int ks = 0; ks < 4; ++ks){
      float4 a0 = *(const float4*)(xr + ks*16);
      float4 a1 = *(const float4*)(xr + ks*16 + 4);
      uint4 u;
      u.x = pk2(a0.x, a0.y); u.y = pk2(a0.z, a0.w);
      u.z = pk2(a1.x, a1.y); u.w = pk2(a1.z, a1.w);
      af[ks] = __builtin_bit_cast(bf16x8, u);
    }
  }

  f32x16 acc0 = zero16(), acc1 = zero16();
  {
    // B: col = lane&31, k = (lane>>5)*8 + i; read from W^T [e][64]
    const uint16_t* w0p = Wt + (size_t)(cb*64 + col)*64 + hi*8;
    const uint16_t* w1p = w0p + 32*64;
    #pragma unroll
    for (int ks = 0; ks < 4; ++ks){
      bf16x8 b0 = *(const bf16x8*)(w0p + ks*16);
      bf16x8 b1 = *(const bf16x8*)(w1p + ks*16);
      acc0 = __builtin_amdgcn_mfma_f32_32x32x16_bf16(af[ks], b0, acc0, 0, 0, 0);
      acc1 = __builtin_amdgcn_mfma_f32_32x32x16_bf16(af[ks], b1, acc1, 0, 0, 0);
    }
  }

  uint16_t* Qg  = (uint16_t*)(ws + WS_QG);
  uint16_t* Kg  = (uint16_t*)(ws + WS_KG);
  uint16_t* Vtg = (uint16_t*)(ws + WS_VTG);
  // D: col = lane&31, row = (r&3) + 8*(r>>2) + 4*(lane>>5)   [m74/m101 verified]
  #pragma unroll
  for (int r = 0; r < 16; ++r){
    int row  = rt*32 + (r&3) + 8*(r>>2) + 4*hi;    // global token
    int b    = row >> 12, ltok = row & 4095;
    uint16_t v0 = bf16b(acc0[r]), v1 = bf16b(acc1[r]);
    if (mm == 2){
      Vtg[(size_t)((b*8 + cb)*64 + col     )*4096 + ltok] = v0;
      Vtg[(size_t)((b*8 + cb)*64 + col + 32)*4096 + ltok] = v1;
    } else {
      uint16_t* G = mm ? Kg : Qg;
      size_t base = (size_t)((b*8 + cb)*4096 + ltok)*64;
      G[base + col]      = v0;
      G[base + col + 32] = v1;
    }
  }
}

// ---------------- kernel 2: flash attention ----------------
// grid 512 = 16 (b,h) x 32 q-tiles(128).  4 waves x 32 q-rows each.
// S^T = K·Q^T (lane owns q = lane&31) -> lane-local softmax -> O^T = V^T·P.
__global__ __launch_bounds__(256,2) void attn_fa(char* __restrict__ ws){
  const int lane = threadIdx.x & 63;
  const int wave = threadIdx.x >> 6;
  const int qt   = blockIdx.x & 31;
  const int bh   = blockIdx.x >> 5;
  const int col  = lane & 31, hi = lane >> 5;

  const uint16_t* Qg  = (const uint16_t*)(ws + WS_QG)  + (size_t)bh*262144;
  const uint16_t* Kg  = (const uint16_t*)(ws + WS_KG)  + (size_t)bh*262144;
  const uint16_t* Vtg = (const uint16_t*)(ws + WS_VTG) + (size_t)bh*262144;
  uint16_t* attn = (uint16_t*)(ws + WS_ATTN);

  // LDS: K dbuf 2x4KB | V^T dbuf 2x4KB | O^T transpose pad [4][64][33] f32
  __shared__ __align__(16) char smem[50176];
  char* kb0 = smem;
  char* kb1 = smem + 4096;
  char* vb0 = smem + 8192;
  char* vb1 = smem + 12288;
  float* otl = (float*)(smem + 16384);

  const int qbase = qt*128 + wave*32;

  // Q fragments (B-operand): col = q = lane&31, k = hi*8 + i (+16*ds)
  bf16x8 qf[4];
  {
    const uint16_t* qr = Qg + (size_t)(qbase + col)*64 + hi*8;
    #pragma unroll
    for (int ds = 0; ds < 4; ++ds) qf[ds] = *(const bf16x8*)(qr + ds*16);
  }

  // staging geometry (reg-staged, XOR-swizzled LDS writes)
  const int kr = wave*8  + (lane >> 3), kj = lane & 7;   // K rows 0..31, 16B slot
  const int vr = wave*16 + (lane >> 2), vj = lane & 3;   // V^T rows 0..63
  const int kDst = (kr*128 + kj*16) ^ ((kr & 7) << 4);
  const int vDst = (vr*64  + vj*16) ^ ((vr & 3) << 4);
  const uint16_t* kSrcBase = Kg  + (size_t)kr*64  + kj*8;   // + t*2048 elems
  const uint16_t* vSrcBase = Vtg + (size_t)vr*4096 + vj*8;  // + t*32 elems

  f32x16 ot0 = zero16(), ot1 = zero16();
  float mrun = -1e30f, lrun = 0.0f;

  // prologue: stage tile 0
  {
    uint4 k0 = *(const uint4*)(kSrcBase);
    uint4 v0 = *(const uint4*)(vSrcBase);
    *(uint4*)(kb0 + kDst) = k0;
    *(uint4*)(vb0 + vDst) = v0;
  }
  __syncthreads();

  uint4 kreg, vreg;
  for (int t = 0; t < 128; ++t){
    const bool last = (t == 127);
    if (!last){  // issue next-tile loads early (hide under compute)
      kreg = *(const uint4*)(kSrcBase + (size_t)(t+1)*2048);
      vreg = *(const uint4*)(vSrcBase + (size_t)(t+1)*32);
    }
    const char* kb = (t & 1) ? kb1 : kb0;
    const char* vb = (t & 1) ? vb1 : vb0;

    // S^T(32kv x 32q) = K · Q^T over d=64 (4 mfma)
    f32x16 s = zero16();
    #pragma unroll
    for (int ds = 0; ds < 4; ++ds){
      bf16x8 kf = *(const bf16x8*)(kb + ((col*128 + hi*16 + ds*32) ^ ((col & 7) << 4)));
      s = __builtin_amdgcn_mfma_f32_32x32x16_bf16(kf, qf[ds], s, 0, 0, 0);
    }

    // online softmax in exp2 domain (scale pre-folded into Q)
    float tmax = s[0];
    #pragma unroll
    for (int r = 1; r < 16; ++r) tmax = fmaxf(tmax, s[r]);
    tmax = fmaxf(tmax, __shfl_xor(tmax, 32));
    const bool skip = __all(tmax <= mrun) != 0;
    float mnew = skip ? mrun : fmaxf(mrun, tmax);
    float p[16];
    #pragma unroll
    for (int r = 0; r < 16; ++r) p[r] = __builtin_amdgcn_exp2f(s[r] - mnew);
    float rs = 0.0f;
    #pragma unroll
    for (int r = 0; r < 16; ++r) rs += p[r];
    rs += __shfl_xor(rs, 32);
    if (!skip){
      float al = __builtin_amdgcn_exp2f(mrun - mnew);
      lrun = lrun * al + rs;
      mrun = mnew;
      #pragma unroll
      for (int r = 0; r < 16; ++r){ ot0[r] *= al; ot1[r] *= al; }
    } else {
      lrun += rs;
    }

    // pack P (f32 regs, C/D layout) -> B-operand bf16 frags via permlane32_swap
    uint32_t w0 = pk2(p[0],  p[1]),  w1 = pk2(p[2],  p[3]);
    uint32_t w2 = pk2(p[4],  p[5]),  w3 = pk2(p[6],  p[7]);
    uint32_t w4 = pk2(p[8],  p[9]),  w5 = pk2(p[10], p[11]);
    uint32_t w6 = pk2(p[12], p[13]), w7 = pk2(p[14], p[15]);
    plswap(w0, w2); plswap(w1, w3); plswap(w4, w6); plswap(w5, w7);
    uint4 u0; u0.x = w0; u0.y = w1; u0.z = w2; u0.w = w3;
    uint4 u1; u1.x = w4; u1.y = w5; u1.z = w6; u1.w = w7;
    bf16x8 pf0 = __builtin_bit_cast(bf16x8, u0);   // kv 0..15
    bf16x8 pf1 = __builtin_bit_cast(bf16x8, u1);   // kv 16..31

    // O^T(64dv x 32q) += V^T-tile · P   (4 mfma)
    {
      bf16x8 vf;
      vf  = *(const bf16x8*)(vb + ((col*64 + hi*16     ) ^ ((col & 3) << 4)));
      ot0 = __builtin_amdgcn_mfma_f32_32x32x16_bf16(vf, pf0, ot0, 0, 0, 0);
      vf  = *(const bf16x8*)(vb + ((col*64 + hi*16 + 32) ^ ((col & 3) << 4)));
      ot0 = __builtin_amdgcn_mfma_f32_32x32x16_bf16(vf, pf1, ot0, 0, 0, 0);
      const int dv1 = col + 32;
      vf  = *(const bf16x8*)(vb + ((dv1*64 + hi*16     ) ^ ((dv1 & 3) << 4)));
      ot1 = __builtin_amdgcn_mfma_f32_32x32x16_bf16(vf, pf0, ot1, 0, 0, 0);
      vf  = *(const bf16x8*)(vb + ((dv1*64 + hi*16 + 32) ^ ((dv1 & 3) << 4)));
      ot1 = __builtin_amdgcn_mfma_f32_32x32x16_bf16(vf, pf1, ot1, 0, 0, 0);
    }

    if (!last){  // write next tile into the other buffer (readers finished it)
      char* kbn = (t & 1) ? kb0 : kb1;
      char* vbn = (t & 1) ? vb0 : vb1;
      *(uint4*)(kbn + kDst) = kreg;
      *(uint4*)(vbn + vDst) = vreg;
    }
    __syncthreads();
  }

  // epilogue: normalize (q is lane-local!) and transpose via LDS for coalesced store
  float inv = 1.0f / lrun;
  #pragma unroll
  for (int r = 0; r < 16; ++r){ ot0[r] *= inv; ot1[r] *= inv; }

  float* ow = otl + wave*2112;   // [64][33]
  #pragma unroll
  for (int r = 0; r < 16; ++r){
    int dv = (r&3) + 8*(r>>2) + 4*hi;
    ow[dv*33 + col]        = ot0[r];
    ow[(dv + 32)*33 + col] = ot1[r];
  }
  __syncthreads();

  {
    int tq = threadIdx.x >> 1, dh = threadIdx.x & 1;   // q-row 0..127, dv-half
    const float* orow = otl + (tq >> 5)*2112 + (tq & 31);
    int token = (bh >> 3)*4096 + qt*128 + tq;
    uint16_t* arow = attn + (size_t)token*512 + (bh & 7)*64 + dh*32;
    #pragma unroll
    for (int j4 = 0; j4 < 4; ++j4){
      int dd = dh*32 + j4*8;
      uint4 u;
      u.x = pk2(orow[(dd+0)*33], orow[(dd+1)*33]);
      u.y = pk2(orow[(dd+2)*33], orow[(dd+3)*33]);
      u.z = pk2(orow[(dd+4)*33], orow[(dd+5)*33]);
      u.w = pk2(orow[(dd+6)*33], orow[(dd+7)*33]);
      *(uint4*)(arow + j4*8) = u;
    }
  }
}

// ---------------- kernel 3: output projection + bias ----------------
__global__ __launch_bounds__(256,2) void out_proj(const char* __restrict__ ws,
                                                  const float* __restrict__ bu,
                                                  float* __restrict__ out){
  const int lane = threadIdx.x & 63;
  const int col  = lane & 31, hi = lane >> 5;
  const int rt   = blockIdx.x*4 + (threadIdx.x >> 6);   // 0..255

  const uint16_t* attn = (const uint16_t*)(ws + WS_ATTN);
  const uint16_t* Wut  = (const uint16_t*)(ws + WS_WUT);

  f32x16 a0 = zero16(), a1 = zero16();
  const uint16_t* ar  = attn + (size_t)(rt*32 + col)*512 + hi*8;
  const uint16_t* b0p = Wut + (size_t)col*512 + hi*8;
  const uint16_t* b1p = b0p + 32*512;
  #pragma unroll 8
  for (int ks = 0; ks < 32; ++ks){
    bf16x8 af = *(const bf16x8*)(ar  + ks*16);
    bf16x8 b0 = *(const bf16x8*)(b0p + ks*16);
    bf16x8 b1 = *(const bf16x8*)(b1p + ks*16);
    a0 = __builtin_amdgcn_mfma_f32_32x32x16_bf16(af, b0, a0, 0, 0, 0);
    a1 = __builtin_amdgcn_mfma_f32_32x32x16_bf16(af, b1, a1, 0, 0, 0);
  }
  float bias0 = bu[col], bias1 = bu[col + 32];
  #pragma unroll
  for (int r = 0; r < 16; ++r){
    int row = rt*32 + (r&3) + 8*(r>>2) + 4*hi;
    out[(size_t)row*64 + col]      = a0[r] + bias0;
    out[(size_t)row*64 + col + 32] = a1[r] + bias1;
  }
}

// ---------------- launch ----------------
extern "C" void kernel_launch(void* const* d_in, const int* in_sizes, int n_in,
                              void* d_out, int out_size, void* d_ws, size_t ws_size,
                              hipStream_t stream){
  const float* x  = (const float*)d_in[0];
  const float* Wq = (const float*)d_in[1];
  const float* Wk = (const float*)d_in[2];
  const float* Wv = (const float*)d_in[3];
  const float* Wu = (const float*)d_in[4];
  const float* bu = (const float*)d_in[5];
  char*  ws  = (char*)d_ws;
  float* out = (float*)d_out;

  prep_w  <<<dim3(512),  dim3(256), 0, stream>>>(Wq, Wk, Wv, Wu, ws);
  qkv_proj<<<dim3(1536), dim3(256), 0, stream>>>(x, ws);
  attn_fa <<<dim3(512),  dim3(256), 0, stream>>>(ws);
  out_proj<<<dim3(64),   dim3(256), 0, stream>>>(ws, bu, out);
}